// Round 6
// baseline (1365.274 us; speedup 1.0000x reference)
//
#include <hip/hip_runtime.h>
#include <hip/hip_bf16.h>
#include <math.h>

// ---------------------------------------------------------------------------
// InfNet: 2-layer GCN + Weibull epilogue.
// GEMMs: bf16x3 split one-pass [Ah|Al|Ah]*[Bh;Bh;Bl], MFMA 16x16x32, fp32 acc,
//        epilogue writes chunk-major T[ch][node][16] for L2-resident gathers.
// Aggregations: feature-chunk phases (3.2 MB slice < 4 MB XCD L2), grid ordered
//        chunk-slowest so co-resident blocks share the slice.
// ---------------------------------------------------------------------------

typedef unsigned short ushort_t;
typedef __attribute__((ext_vector_type(8))) short bf16x8;
typedef __attribute__((ext_vector_type(4))) float f32x4;

__device__ __forceinline__ ushort_t f2bf(float f) {
    union { float f; unsigned u; } x; x.f = f;
    unsigned r = x.u + 0x7FFF + ((x.u >> 16) & 1);   // RNE
    return (ushort_t)(r >> 16);
}
__device__ __forceinline__ float bf2f(ushort_t s) {
    union { unsigned u; float f; } x; x.u = ((unsigned)s) << 16; return x.f;
}

__device__ __forceinline__ void async_copy16(const void* gsrc, void* ldst) {
    __builtin_amdgcn_global_load_lds(
        (const __attribute__((address_space(1))) unsigned int*)gsrc,
        (__attribute__((address_space(3))) unsigned int*)ldst,
        16, 0, 0);
}

// ---------------- graph preprocessing ----------------

__global__ __launch_bounds__(256) void count_kernel(const int* __restrict__ dst,
                                                    int* __restrict__ cnt, int E)
{
    int e = blockIdx.x * blockDim.x + threadIdx.x;
    if (e < E) atomicAdd(&cnt[dst[e]], 1);
}

__global__ __launch_bounds__(1024) void scan_local(const int* __restrict__ cnt,
                                                   int* __restrict__ rowptr,
                                                   float* __restrict__ dinv,
                                                   int* __restrict__ blksum, int N)
{
    __shared__ int wsum[16];
    int tid = threadIdx.x, lane = tid & 63, wid = tid >> 6;
    int i = blockIdx.x * 1024 + tid;
    int v = (i < N) ? cnt[i] : 0;
    if (i < N) dinv[i] = rsqrtf((float)(v + 1));
    int s = v;
#pragma unroll
    for (int off = 1; off < 64; off <<= 1) {
        int t = __shfl_up(s, off, 64);
        if (lane >= off) s += t;
    }
    if (lane == 63) wsum[wid] = s;
    __syncthreads();
    if (tid < 16) {
        int w = wsum[tid];
#pragma unroll
        for (int off = 1; off < 16; off <<= 1) {
            int t = __shfl_up(w, off, 64);
            if (tid >= off) w += t;
        }
        wsum[tid] = w;
    }
    __syncthreads();
    int excl = s - v + (wid ? wsum[wid - 1] : 0);
    if (i < N) rowptr[i] = excl;
    if (tid == 0) blksum[blockIdx.x] = wsum[15];
}

__global__ __launch_bounds__(64) void scan_blk(const int* __restrict__ blksum,
                                               int* __restrict__ blkoff,
                                               int nblk, int* __restrict__ rowptr, int N)
{
    int tid = threadIdx.x;
    int v = (tid < nblk) ? blksum[tid] : 0;
    int s = v;
#pragma unroll
    for (int off = 1; off < 64; off <<= 1) {
        int t = __shfl_up(s, off, 64);
        if (tid >= off) s += t;
    }
    if (tid < nblk) blkoff[tid] = s - v;
    if (tid == nblk - 1) rowptr[N] = s;
}

__global__ __launch_bounds__(256) void scan_add(int* __restrict__ rowptr,
                                                int* __restrict__ cursor,
                                                const int* __restrict__ blkoff, int N)
{
    int i = blockIdx.x * blockDim.x + threadIdx.x;
    if (i < N) {
        int r = rowptr[i] + blkoff[i >> 10];
        rowptr[i] = r;
        cursor[i] = r;
    }
}

__global__ __launch_bounds__(256) void scatter_kernel(const int* __restrict__ src,
                                                      const int* __restrict__ dst,
                                                      int* __restrict__ cursor,
                                                      int* __restrict__ col, int E)
{
    int e = blockIdx.x * blockDim.x + threadIdx.x;
    if (e < E) {
        int d = dst[e];
        int pos = atomicAdd(&cursor[d], 1);
        col[pos] = src[e];
    }
}

// ---------------- operand conversion (bf16 hi/lo split) ----------------

__global__ __launch_bounds__(256) void conv_x(const float* __restrict__ x,
                                              ushort_t* __restrict__ Abig,
                                              int M, int M_pad)
{
    int id = blockIdx.x * blockDim.x + threadIdx.x;
    int r = id >> 7, q = id & 127;
    if (r >= M_pad) return;
    float4 v = make_float4(0.f, 0.f, 0.f, 0.f);
    if (r < M) v = *reinterpret_cast<const float4*>(&x[(size_t)r * 512 + q * 4]);
    ushort4 h, l;
    h.x = f2bf(v.x); l.x = f2bf(v.x - bf2f(h.x));
    h.y = f2bf(v.y); l.y = f2bf(v.y - bf2f(h.y));
    h.z = f2bf(v.z); l.z = f2bf(v.z - bf2f(h.z));
    h.w = f2bf(v.w); l.w = f2bf(v.w - bf2f(h.w));
    ushort_t* rowp = Abig + (size_t)r * 1024;
    *reinterpret_cast<ushort4*>(rowp + q * 4)       = h;
    *reinterpret_cast<ushort4*>(rowp + 512 + q * 4) = l;
}

__global__ __launch_bounds__(256) void conv_w0(const float* __restrict__ W0,
                                               ushort_t* __restrict__ BT)
{
    int id = blockIdx.x * blockDim.x + threadIdx.x;
    int k = id & 511, n = id >> 9;
    if (n >= 256) return;
    float v = W0[(size_t)k * 256 + n];
    ushort_t h = f2bf(v);
    ushort_t l = f2bf(v - bf2f(h));
    ushort_t* rowp = BT + (size_t)n * 1536;
    rowp[k] = h; rowp[512 + k] = h; rowp[1024 + k] = l;
}

__global__ __launch_bounds__(256) void conv_w1(const float* __restrict__ W1,
                                               ushort_t* __restrict__ BT,
                                               float* __restrict__ W1col)
{
    int id = blockIdx.x * blockDim.x + threadIdx.x;
    int k = id & 255, n = id >> 8;
    if (n >= 128) return;
    float v = W1[(size_t)k * 129 + n];
    ushort_t h = f2bf(v);
    ushort_t l = f2bf(v - bf2f(h));
    ushort_t* rowp = BT + (size_t)n * 768;
    rowp[k] = h; rowp[256 + k] = h; rowp[512 + k] = l;
    if (n == 0) W1col[k] = W1[(size_t)k * 129 + 128];
}

// ---------------- MFMA GEMM: C = A(M x K) * BT(N x K)^T ----------------
// A k-index wraps at kwrap. C written chunk-major: C[(cc>>4)*cstr + r][cc&15].
__global__ __launch_bounds__(256) void gemm_bf16(const ushort_t* __restrict__ A, int lda,
                                                 const ushort_t* __restrict__ BT, int ldbt,
                                                 float* __restrict__ C, int cstr,
                                                 int M, int K, int kwrap)
{
    __shared__ short As[128 * 32];
    __shared__ short Bs[128 * 32];

    int tid  = threadIdx.x;
    int w    = tid >> 6;
    int lane = tid & 63;
    int lm   = lane & 15;
    int lq   = lane >> 4;
    int bm   = blockIdx.x * 128;
    int bn   = blockIdx.y * 128;
    int wr   = (w >> 1) * 64;
    int wc   = (w & 1) * 64;

    f32x4 acc[4][4];
#pragma unroll
    for (int i = 0; i < 4; ++i)
#pragma unroll
        for (int j = 0; j < 4; ++j) acc[i][j] = (f32x4)(0.f);

    int srow = (lane >> 2);
    int scol = (lane & 3) * 16;

    for (int k0 = 0; k0 < K; k0 += 32) {
        int ka = (k0 < kwrap) ? k0 : (k0 - kwrap);
#pragma unroll
        for (int q = 0; q < 2; ++q) {
            int r = w * 32 + q * 16 + srow;
            const char* ga = (const char*)A + ((size_t)(bm + r) * lda + ka) * 2 + scol;
            async_copy16(ga, (char*)As + (size_t)(w * 32 + q * 16) * 64);
        }
#pragma unroll
        for (int q = 0; q < 2; ++q) {
            int r = w * 32 + q * 16 + srow;
            const char* gb = (const char*)BT + ((size_t)(bn + r) * ldbt + k0) * 2 + scol;
            async_copy16(gb, (char*)Bs + (size_t)(w * 32 + q * 16) * 64);
        }
        __syncthreads();

        bf16x8 afr[4], bfr[4];
#pragma unroll
        for (int mi = 0; mi < 4; ++mi)
            afr[mi] = *reinterpret_cast<const bf16x8*>(&As[(wr + mi * 16 + lm) * 32 + lq * 8]);
#pragma unroll
        for (int ni = 0; ni < 4; ++ni)
            bfr[ni] = *reinterpret_cast<const bf16x8*>(&Bs[(wc + ni * 16 + lm) * 32 + lq * 8]);
#pragma unroll
        for (int mi = 0; mi < 4; ++mi)
#pragma unroll
            for (int ni = 0; ni < 4; ++ni)
                acc[mi][ni] = __builtin_amdgcn_mfma_f32_16x16x32_bf16(
                    afr[mi], bfr[ni], acc[mi][ni], 0, 0, 0);
        __syncthreads();
    }

#pragma unroll
    for (int mi = 0; mi < 4; ++mi) {
#pragma unroll
        for (int ni = 0; ni < 4; ++ni) {
            int rbase = bm + wr + mi * 16 + lq * 4;
            int ch    = (bn + wc) / 16 + ni;       // wave-uniform chunk index
#pragma unroll
            for (int e = 0; e < 4; ++e) {
                int r = rbase + e;
                if (r < M)
                    C[((size_t)ch * cstr + r) * 16 + lm] = acc[mi][ni][e];
            }
        }
    }
}

// ---------------- fused pieces ----------------

__device__ __forceinline__ float softplus_f(float x)
{
    return fmaxf(x, 0.f) + log1pf(expf(-fabsf(x)));
}

// layer-1 aggregation + softplus, chunked. Grid (ceil(N/4), 16); block 256 = 4 waves.
// Wave = one node; quad q = edge slot (16 in flight), lane&3 = float4 of chunk.
__global__ __launch_bounds__(256) void agg1_chunk(const float* __restrict__ T1c,
                                                  const float* __restrict__ dinv,
                                                  const int* __restrict__ rowptr,
                                                  const int* __restrict__ col,
                                                  ushort_t* __restrict__ H1big, int N)
{
    int node = blockIdx.x * 4 + (threadIdx.x >> 6);
    if (node >= N) return;
    int lane = threadIdx.x & 63;
    int q    = lane >> 2;        // edge slot 0..15
    int fq   = lane & 3;         // float4 index within 16-feature chunk
    int ch   = blockIdx.y;       // 0..15
    const float* slice = T1c + (size_t)ch * N * 16;

    float di  = dinv[node];
    int   beg = rowptr[node], end = rowptr[node + 1];

    float4 acc = make_float4(0.f, 0.f, 0.f, 0.f);
    for (int e0 = beg; e0 < end; e0 += 16) {
        int idx = e0 + q;
        if (idx < end) {
            int   s = col[idx];
            float w = dinv[s];
            float4 v = *reinterpret_cast<const float4*>(&slice[(size_t)s * 16 + fq * 4]);
            acc.x = fmaf(w, v.x, acc.x);
            acc.y = fmaf(w, v.y, acc.y);
            acc.z = fmaf(w, v.z, acc.z);
            acc.w = fmaf(w, v.w, acc.w);
        }
    }
    // reduce over the 16 slots (stride-4 lanes share fq)
#pragma unroll
    for (int off = 32; off >= 4; off >>= 1) {
        acc.x += __shfl_down(acc.x, off, 64);
        acc.y += __shfl_down(acc.y, off, 64);
        acc.z += __shfl_down(acc.z, off, 64);
        acc.w += __shfl_down(acc.w, off, 64);
    }
    if (q == 0) {
        float4 self = *reinterpret_cast<const float4*>(&slice[(size_t)node * 16 + fq * 4]);
        float4 o;
        o.x = softplus_f((acc.x + self.x * di) * di);
        o.y = softplus_f((acc.y + self.y * di) * di);
        o.z = softplus_f((acc.z + self.z * di) * di);
        o.w = softplus_f((acc.w + self.w * di) * di);
        ushort4 h, l;
        h.x = f2bf(o.x); l.x = f2bf(o.x - bf2f(h.x));
        h.y = f2bf(o.y); l.y = f2bf(o.y - bf2f(h.y));
        h.z = f2bf(o.z); l.z = f2bf(o.z - bf2f(h.z));
        h.w = f2bf(o.w); l.w = f2bf(o.w - bf2f(h.w));
        ushort_t* rowp = H1big + (size_t)node * 512 + ch * 16 + fq * 4;
        *reinterpret_cast<ushort4*>(rowp)       = h;
        *reinterpret_cast<ushort4*>(rowp + 256) = l;
    }
}

// kappa column: T2k[i] = dot(H1[i,:], W1col), H1 reconstructed hi+lo.
__global__ __launch_bounds__(256) void kappa_col_kernel(const ushort_t* __restrict__ H1big,
                                                        const float* __restrict__ W1col,
                                                        float* __restrict__ T2k, int N)
{
    __shared__ float w[256];
    int tid = threadIdx.x;
    w[tid] = W1col[tid];
    __syncthreads();
    int lane = tid & 63;
    int wid  = tid >> 6;
    int row  = blockIdx.x * 4 + wid;
    if (row >= N) return;
    const ushort_t* rowp = H1big + (size_t)row * 512;
    float s = 0.f;
#pragma unroll
    for (int k = lane; k < 256; k += 64) {
        float hv = bf2f(rowp[k]) + bf2f(rowp[256 + k]);
        s = fmaf(hv, w[k], s);
    }
#pragma unroll
    for (int off = 32; off > 0; off >>= 1)
        s += __shfl_down(s, off, 64);
    if (lane == 0) T2k[row] = s;
}

// per-node kappa aggregation + Weibull gamma factor. Wave per node.
__global__ __launch_bounds__(256) void kappa_node(const float* __restrict__ T2k,
                                                  const float* __restrict__ dinv,
                                                  const int* __restrict__ rowptr,
                                                  const int* __restrict__ col,
                                                  float* __restrict__ kap_out,
                                                  float* __restrict__ gfac, int N)
{
    int node = blockIdx.x * 4 + (threadIdx.x >> 6);
    if (node >= N) return;
    int lane = threadIdx.x & 63;
    float di  = dinv[node];
    int   beg = rowptr[node], end = rowptr[node + 1];
    float acck = 0.f;
    for (int e = beg + lane; e < end; e += 64) {
        int s = col[e];
        acck = fmaf(dinv[s], T2k[s], acck);
    }
#pragma unroll
    for (int off = 32; off > 0; off >>= 1)
        acck += __shfl_down(acck, off, 64);
    if (lane == 0) {
        float ak = (acck + T2k[node] * di) * di;
        float kv = softplus_f(ak) + 0.1f;
        kap_out[node] = kv;
        gfac[node]    = expf(lgammaf(1.0f + 1.0f / kv));
    }
}

// layer-2 aggregation + softplus + Weibull epilogue, chunked. Grid (ceil(N/4), 8).
__global__ __launch_bounds__(256) void agg2_chunk(const float* __restrict__ T2c,
                                                  const float* __restrict__ dinv,
                                                  const int* __restrict__ rowptr,
                                                  const int* __restrict__ col,
                                                  const float* __restrict__ gfac,
                                                  float* __restrict__ z_out,
                                                  float* __restrict__ lbd_out, int N)
{
    int node = blockIdx.x * 4 + (threadIdx.x >> 6);
    if (node >= N) return;
    int lane = threadIdx.x & 63;
    int q    = lane >> 2;
    int fq   = lane & 3;
    int ch   = blockIdx.y;       // 0..7
    const float* slice = T2c + (size_t)ch * N * 16;

    float di  = dinv[node];
    int   beg = rowptr[node], end = rowptr[node + 1];

    float4 acc = make_float4(0.f, 0.f, 0.f, 0.f);
    for (int e0 = beg; e0 < end; e0 += 16) {
        int idx = e0 + q;
        if (idx < end) {
            int   s = col[idx];
            float w = dinv[s];
            float4 v = *reinterpret_cast<const float4*>(&slice[(size_t)s * 16 + fq * 4]);
            acc.x = fmaf(w, v.x, acc.x);
            acc.y = fmaf(w, v.y, acc.y);
            acc.z = fmaf(w, v.z, acc.z);
            acc.w = fmaf(w, v.w, acc.w);
        }
    }
#pragma unroll
    for (int off = 32; off >= 4; off >>= 1) {
        acc.x += __shfl_down(acc.x, off, 64);
        acc.y += __shfl_down(acc.y, off, 64);
        acc.z += __shfl_down(acc.z, off, 64);
        acc.w += __shfl_down(acc.w, off, 64);
    }
    if (q == 0) {
        float4 self = *reinterpret_cast<const float4*>(&slice[(size_t)node * 16 + fq * 4]);
        float4 sp;
        sp.x = softplus_f((acc.x + self.x * di) * di);
        sp.y = softplus_f((acc.y + self.y * di) * di);
        sp.z = softplus_f((acc.z + self.z * di) * di);
        sp.w = softplus_f((acc.w + self.w * di) * di);
        float g = gfac[node];
        size_t o = (size_t)node * 128 + ch * 16 + fq * 4;
        *reinterpret_cast<float4*>(&lbd_out[o]) = sp;
        float4 zv = make_float4(sp.x * g, sp.y * g, sp.z * g, sp.w * g);
        *reinterpret_cast<float4*>(&z_out[o]) = zv;
    }
}

extern "C" void kernel_launch(void* const* d_in, const int* in_sizes, int n_in,
                              void* d_out, int out_size, void* d_ws, size_t ws_size,
                              hipStream_t stream)
{
    const float* x  = (const float*)d_in[0];
    const int*   ei = (const int*)d_in[1];
    const float* W0 = (const float*)d_in[2];
    const float* W1 = (const float*)d_in[3];

    const int N = in_sizes[0] / 512;      // 50000
    const int E = in_sizes[1] / 2;        // 1600000
    const int* src = ei;
    const int* dst = ei + E;

    const int mblocks = (N + 127) / 128;   // 391
    const int M_pad   = mblocks * 128;     // 50048
    const int nchunk  = (N + 1023) / 1024; // 49
    const int ngrp    = (N + 3) / 4;       // 12500

    char* w = (char*)d_ws;
    size_t off = 0;
    auto take = [&](size_t bytes) -> void* {
        void* p = (void*)(w + off);
        off = (off + bytes + 255) & ~(size_t)255;
        return p;
    };
    int*      cnt    = (int*)take((size_t)N * 4);
    int*      rowptr = (int*)take((size_t)(N + 1) * 4);
    int*      cursor = (int*)take((size_t)N * 4);
    float*    dinv   = (float*)take((size_t)N * 4);
    int*      col    = (int*)take((size_t)E * 4);
    int*      blksum = (int*)take(64 * 4);
    int*      blkoff = (int*)take(64 * 4);
    ushort_t* W0bigT = (ushort_t*)take((size_t)256 * 1536 * 2);
    ushort_t* W1bigT = (ushort_t*)take((size_t)128 * 768 * 2);
    float*    W1col  = (float*)take((size_t)256 * 4);
    float*    T2k    = (float*)take((size_t)N * 4);
    float*    gfac   = (float*)take((size_t)N * 4);
    float*    T1c    = (float*)take((size_t)N * 256 * 4);  // chunk-major [16][N][16]
    float*    T2c    = T1c;               // T1c dead after agg1; reuse [8][N][16]
    ushort_t* Abig   = (ushort_t*)take((size_t)M_pad * 1024 * 2);
    ushort_t* H1big  = Abig;              // Abig dead after gemm1

    float* z_out   = (float*)d_out;
    float* lbd_out = z_out + (size_t)N * 128;
    float* kap_out = lbd_out + (size_t)N * 128;

    hipMemsetAsync(cnt, 0, (size_t)N * 4, stream);
    count_kernel<<<(E + 255) / 256, 256, 0, stream>>>(dst, cnt, E);
    scan_local<<<nchunk, 1024, 0, stream>>>(cnt, rowptr, dinv, blksum, N);
    scan_blk<<<1, 64, 0, stream>>>(blksum, blkoff, nchunk, rowptr, N);
    scan_add<<<(N + 255) / 256, 256, 0, stream>>>(rowptr, cursor, blkoff, N);
    scatter_kernel<<<(E + 255) / 256, 256, 0, stream>>>(src, dst, cursor, col, E);

    conv_x<<<(M_pad * 128) / 256, 256, 0, stream>>>(x, Abig, N, M_pad);
    conv_w0<<<(256 * 512) / 256, 256, 0, stream>>>(W0, W0bigT);
    conv_w1<<<(128 * 256) / 256, 256, 0, stream>>>(W1, W1bigT, W1col);

    // GEMM1: T1c = x @ W0 (chunk-major out). K=1536, A wraps at 1024.
    dim3 g1(mblocks, 2);
    gemm_bf16<<<g1, 256, 0, stream>>>(Abig, 1024, W0bigT, 1536, T1c, N, N, 1536, 1024);

    // layer-1 aggregation, 16 feature-chunk phases (chunk = blockIdx.y, slowest).
    agg1_chunk<<<dim3(ngrp, 16), 256, 0, stream>>>(T1c, dinv, rowptr, col, H1big, N);

    // GEMM2: T2c = H1 @ W1main (chunk-major out). K=768, A wraps at 512.
    dim3 g2(mblocks, 1);
    gemm_bf16<<<g2, 256, 0, stream>>>(H1big, 512, W1bigT, 768, T2c, N, N, 768, 512);

    kappa_col_kernel<<<(N + 3) / 4, 256, 0, stream>>>(H1big, W1col, T2k, N);
    kappa_node<<<ngrp, 256, 0, stream>>>(T2k, dinv, rowptr, col, kap_out, gfac, N);

    // layer-2 aggregation + epilogue, 8 chunk phases.
    agg2_chunk<<<dim3(ngrp, 8), 256, 0, stream>>>(T2c, dinv, rowptr, col, gfac,
                                                  z_out, lbd_out, N);
}